// Round 7
// baseline (279.340 us; speedup 1.0000x reference)
//
#include <hip/hip_runtime.h>
#include <hip/hip_bf16.h>

#define Bb 8
#define Ll 512
#define Dd 32
#define Nn 64
#define Hh 64
#define G4 256  // 4*H

#define L2E  1.4426950408889634f   // log2(e)
#define L2E2 2.8853900817779268f   // 2*log2(e)

typedef _Float16 h2_t __attribute__((ext_vector_type(2)));

__device__ __forceinline__ float fast_rcp(float x) { return __builtin_amdgcn_rcpf(x); }
// v_exp_f32 computes 2^x directly
__device__ __forceinline__ float fast_exp2(float x) { return __builtin_amdgcn_exp2f(x); }

// sigmoid(x) = rcp(1+exp2(-x*log2e)); saturates gracefully, no clamps
__device__ __forceinline__ float sig2(float x) {
    return fast_rcp(1.f + fast_exp2(-L2E * x));
}
// tanh(x) = 2*sigmoid(2x)-1
__device__ __forceinline__ float tanh2(float x) {
    return fmaf(2.f, fast_rcp(1.f + fast_exp2(-L2E2 * x)), -1.f);
}

__device__ __forceinline__ float fdot2(h2_t a, h2_t b, float c) {
#if __has_builtin(__builtin_amdgcn_fdot2)
    return __builtin_amdgcn_fdot2(a, b, c, false);
#else
    return c + (float)a[0] * (float)b[0] + (float)a[1] * (float)b[1];
#endif
}

// ---------------- Kernel 1: exp-space projections ----------------
// Ex = exp2(2*log2e*(text@Wx^T+b)), Eh = exp2(2*log2e*(text@Wxhat^T+b))
// so that e^{2(wx_i+wxh_j)} = Ex_i * Eh_j in the attention inner loop.
__global__ __launch_bounds__(256) void k_proj(
    const float* __restrict__ text,
    const float* __restrict__ Wx_w, const float* __restrict__ Wx_b,
    const float* __restrict__ Wxh_w, const float* __restrict__ Wxh_b,
    float* __restrict__ Ex, float* __restrict__ Eh) {
    int idx = blockIdx.x * 256 + threadIdx.x;   // B*L*N
    int n = idx & 63;
    int bl = idx >> 6;
    const float4* tr = (const float4*)(text + bl * Dd);
    const float4* w1 = (const float4*)(Wx_w + n * Dd);
    const float4* w2 = (const float4*)(Wxh_w + n * Dd);
    float a0 = 0.f, a1 = 0.f;
#pragma unroll
    for (int q = 0; q < 8; ++q) {
        float4 t4 = tr[q]; float4 x4 = w1[q]; float4 y4 = w2[q];
        a0 += t4.x * x4.x + t4.y * x4.y + t4.z * x4.z + t4.w * x4.w;
        a1 += t4.x * y4.x + t4.y * y4.y + t4.z * y4.z + t4.w * y4.w;
    }
    Ex[idx] = fast_exp2(L2E2 * (a0 + Wx_b[n]));
    Eh[idx] = fast_exp2(L2E2 * (a1 + Wxh_b[n]));
}

// ---------------- Kernel 2: fused attention + Xatt + Gx ----------------
// tanh(wxh+wx) = 1 - 2*rcp(E*F+1) with E=e^{2wxh}, F=e^{2wx} precomputed.
// z = sum_n aw_n tanh(.) = awsum - 2*sum_n aw_n*rcp(E_n*F_n+1).
// Epilogue computes Gx = Xatt@W_ih^T + b_ih + b_hh; Gx layout is
// [t][unit*4 + gate] so k_lstm reads one float4 {i,f,g,o} per unit.
__global__ __launch_bounds__(256) void k_attn(
    const float* __restrict__ text,
    const float* __restrict__ Ex, const float* __restrict__ Eh,
    const float* __restrict__ att_w, const float* __restrict__ att_b,
    const float* __restrict__ W_ih, const float* __restrict__ b_ih,
    const float* __restrict__ b_hh, float* __restrict__ Gx) {
    __shared__ float s_eh[64 * 65];    // Eh tile [n][j] padded
    __shared__ float s_text[32 * 65];  // text tile [d][j] padded
    __shared__ float2 s_fa[4 * 64];    // (F, aw) per (wave-row, n)
    __shared__ float s_A[4 * 64];      // per-wave A chunk
    __shared__ __align__(16) float s_xatt[4][32];  // finished Xatt rows

    int tid = threadIdx.x;
    int bx = blockIdx.x;           // 0..1023
    int b = bx >> 7;               // /128
    int i0 = (bx & 127) << 2;      // *4
    int w = tid >> 6, l = tid & 63;
    int i = i0 + w;

    // stage (F, aw) pairs for this block's 4 i-rows
    s_fa[w * 64 + l] = make_float2(Ex[((b * Ll) + i) * Nn + l], att_w[l]);
    float ab = att_b[0];
    __syncthreads();

    float awsum = 0.f;
#pragma unroll
    for (int n = 0; n < 64; ++n) awsum += s_fa[w * 64 + n].y;
    float zc = awsum + ab;

    float xacc = 0.f;              // lane: d = l&31, half = l>>5
    int d = l & 31, hf = l >> 5;

    for (int jt = 0; jt < 8; ++jt) {
        __syncthreads();
        {   // stage Eh tile [n][j] + text tile [d][j]
            int n = tid & 63; int j4 = tid >> 6;
#pragma unroll
            for (int r = 0; r < 16; ++r) {
                int jl = j4 + r * 4;
                s_eh[n * 65 + jl] = Eh[((b * Ll) + jt * 64 + jl) * Nn + n];
            }
            int dd = tid & 31; int j8 = tid >> 5;
#pragma unroll
            for (int r = 0; r < 8; ++r) {
                int jl = j8 + r * 8;
                s_text[dd * 65 + jl] = text[((b * Ll) + jt * 64 + jl) * Dd + dd];
            }
        }
        __syncthreads();
        float S = 0.f;
#pragma unroll
        for (int n = 0; n < 64; ++n) {
            float E = s_eh[n * 65 + l];
            float2 fa = s_fa[w * 64 + n];
            float r = fast_rcp(fmaf(E, fa.x, 1.f));
            S = fmaf(fa.y, r, S);
        }
        // A = sigmoid(awsum - 2S + ab)
        float A = fast_rcp(1.f + fast_exp2(-L2E * (zc - 2.f * S)));
        s_A[w * 64 + l] = A;
#pragma unroll
        for (int jj = 0; jj < 32; ++jj) {
            int j = hf * 32 + jj;
            xacc += s_A[w * 64 + j] * s_text[d * 65 + j];
        }
    }
    xacc += __shfl_xor(xacc, 32);
    if (l < 32) s_xatt[w][l] = xacc;   // lanes 0..31 hold d = l
    __syncthreads();

    // ---- fused Gx epilogue: thread tid = W_ih row r, rows i0..i0+3 ----
    {
        int r0 = tid;                  // gate-row 0..255
        int gt = r0 >> 6, un = r0 & 63;
        const float4* wr = (const float4*)(W_ih + r0 * Dd);
        float4 wv[8];
#pragma unroll
        for (int q = 0; q < 8; ++q) wv[q] = wr[q];
        float bias = b_ih[r0] + b_hh[r0];
#pragma unroll
        for (int r = 0; r < 4; ++r) {
            const float4* xr = (const float4*)s_xatt[r];  // LDS broadcast reads
            float acc = bias;
#pragma unroll
            for (int q = 0; q < 8; ++q) {
                float4 x4 = xr[q]; float4 w4 = wv[q];
                acc += x4.x * w4.x + x4.y * w4.y + x4.z * w4.z + x4.w * w4.w;
            }
            // layout: [row][unit*4 + gate]
            Gx[((b * Ll) + i0 + r) * G4 + un * 4 + gt] = acc;
        }
    }
}

// ---------------- Kernel 3: LSTM recurrence (ONE WAVE per batch) ----------------
// 64 lanes = 64 units. Lane l holds W_hh rows of all 4 gates of unit l
// (128 VGPRs as half2) and computes full 64-wide dots via v_dot2_f32_f16
// (2 chains/gate). h exchange: ds_write_b16 own h + 8 uniform ds_read_b128
// of the full vector — same-wave DS ops are in-order, so NO barrier at all.
// Gx layout [t][unit*4+gate]: one float4 per lane per step, dist-2 prefetch.
__global__ __launch_bounds__(64) void k_lstm(
    const float* __restrict__ Gx, const float* __restrict__ W_hh,
    const float* __restrict__ dense_w, const float* __restrict__ dense_b,
    float* __restrict__ out) {
    __shared__ __align__(16) _Float16 s_h[64];
    int b = blockIdx.x;
    int l = threadIdx.x;           // unit

    // wreg[g][k] = half2 of W_hh[g*64+l][2k .. 2k+1]
    h2_t wreg[4][32];
#pragma unroll
    for (int g = 0; g < 4; ++g) {
        const float4* wp = (const float4*)(W_hh + (g * 64 + l) * 64);
#pragma unroll
        for (int q = 0; q < 16; ++q) {
            float4 v = wp[q];
            wreg[g][2 * q]     = h2_t{(_Float16)v.x, (_Float16)v.y};
            wreg[g][2 * q + 1] = h2_t{(_Float16)v.z, (_Float16)v.w};
        }
    }

    s_h[l] = (_Float16)0.f;
    float c = 0.f;
    const float4* gxb = (const float4*)Gx + (size_t)b * Ll * 64 + l;  // stride 64 float4 per t
    float4 gx_cur = gxb[0];
    float4 gx_n1  = gxb[64];

    for (int t = 0; t < Ll; ++t) {
        int t2 = (t + 2 < Ll) ? (t + 2) : (Ll - 1);
        float4 gx_n2 = gxb[(size_t)t2 * 64];   // dist-2 prefetch

        // read full h: 8 uniform-address b128 broadcasts (in-order after write)
        h2_t hreg[32];
        const float4* hb = (const float4*)s_h;
#pragma unroll
        for (int q = 0; q < 8; ++q) {
            union { float4 f; h2_t h[4]; } uu;
            uu.f = hb[q];
            hreg[4 * q]     = uu.h[0];
            hreg[4 * q + 1] = uu.h[1];
            hreg[4 * q + 2] = uu.h[2];
            hreg[4 * q + 3] = uu.h[3];
        }

        // 4 gate dots, 2 independent chains each (dep depth 16)
        float a0 = gx_cur.x, a1 = gx_cur.y, a2 = gx_cur.z, a3 = gx_cur.w;
        float b0 = 0.f, b1 = 0.f, b2 = 0.f, b3 = 0.f;
#pragma unroll
        for (int k = 0; k < 16; ++k) {
            a0 = fdot2(hreg[k], wreg[0][k], a0);
            a1 = fdot2(hreg[k], wreg[1][k], a1);
            a2 = fdot2(hreg[k], wreg[2][k], a2);
            a3 = fdot2(hreg[k], wreg[3][k], a3);
            b0 = fdot2(hreg[k + 16], wreg[0][k + 16], b0);
            b1 = fdot2(hreg[k + 16], wreg[1][k + 16], b1);
            b2 = fdot2(hreg[k + 16], wreg[2][k + 16], b2);
            b3 = fdot2(hreg[k + 16], wreg[3][k + 16], b3);
        }
        float ti = a0 + b0, tf = a1 + b1, tg = a2 + b2, to = a3 + b3;

        float gi = sig2(ti);
        float gf = sig2(tf);
        float gg = tanh2(tg);
        float go = sig2(to);
        c = fmaf(gf, c, gi * gg);
        float hh = go * tanh2(c);
        s_h[l] = (_Float16)hh;        // next iter's reads are in-order behind this
        gx_cur = gx_n1;
        gx_n1 = gx_n2;
    }
    // dense head: lanes 0,1 compute the two outputs
    if (l < 2) {
        float a = dense_b[l];
        for (int uu = 0; uu < 64; ++uu)
            a += (float)s_h[uu] * dense_w[l * 64 + uu];
        out[b * 2 + l] = a;
    }
}

extern "C" void kernel_launch(void* const* d_in, const int* in_sizes, int n_in,
                              void* d_out, int out_size, void* d_ws, size_t ws_size,
                              hipStream_t stream) {
    const float* text    = (const float*)d_in[0];
    const float* Wx_w    = (const float*)d_in[1];
    const float* Wx_b    = (const float*)d_in[2];
    const float* Wxh_w   = (const float*)d_in[3];
    const float* Wxh_b   = (const float*)d_in[4];
    const float* att_w   = (const float*)d_in[5];
    const float* att_b   = (const float*)d_in[6];
    const float* W_ih    = (const float*)d_in[7];
    const float* W_hh    = (const float*)d_in[8];
    const float* b_ih    = (const float*)d_in[9];
    const float* b_hh    = (const float*)d_in[10];
    const float* dense_w = (const float*)d_in[11];
    const float* dense_b = (const float*)d_in[12];

    float* ws   = (float*)d_ws;
    float* Ex   = ws;                 // 8*512*64   = 262144
    float* Eh   = ws + 262144;        // 262144
    float* Gx   = ws + 655360;        // 8*512*256  = 1048576
    float* out  = (float*)d_out;

    hipLaunchKernelGGL(k_proj, dim3((Bb * Ll * Nn) / 256), dim3(256), 0, stream,
                       text, Wx_w, Wx_b, Wxh_w, Wxh_b, Ex, Eh);
    hipLaunchKernelGGL(k_attn, dim3(Bb * (Ll / 4)), dim3(256), 0, stream,
                       text, Ex, Eh, att_w, att_b, W_ih, b_ih, b_hh, Gx);
    hipLaunchKernelGGL(k_lstm, dim3(Bb), dim3(64), 0, stream,
                       Gx, W_hh, dense_w, dense_b, out);
}

// Round 8
// 249.582 us; speedup vs baseline: 1.1192x; 1.1192x over previous
//
#include <hip/hip_runtime.h>
#include <hip/hip_bf16.h>

#define Bb 8
#define Ll 512
#define Dd 32
#define Nn 64
#define Hh 64
#define G4 256  // 4*H

#define L2E  1.4426950408889634f   // log2(e)
#define L2E2 2.8853900817779268f   // 2*log2(e)

typedef _Float16 f16x8 __attribute__((ext_vector_type(8)));
typedef float f32x4 __attribute__((ext_vector_type(4)));

__device__ __forceinline__ float fast_rcp(float x) { return __builtin_amdgcn_rcpf(x); }
// v_exp_f32 computes 2^x directly
__device__ __forceinline__ float fast_exp2(float x) { return __builtin_amdgcn_exp2f(x); }

// sigmoid(x) = rcp(1+exp2(-x*log2e)); saturates gracefully, no clamps
__device__ __forceinline__ float sig2(float x) {
    return fast_rcp(1.f + fast_exp2(-L2E * x));
}
// tanh(x) = 2*sigmoid(2x)-1
__device__ __forceinline__ float tanh2(float x) {
    return fmaf(2.f, fast_rcp(1.f + fast_exp2(-L2E2 * x)), -1.f);
}

// ---------------- Kernel 1: exp-space projections ----------------
// Ex = exp2(2*log2e*(text@Wx^T+b)), Eh = exp2(2*log2e*(text@Wxhat^T+b))
// so that e^{2(wx_i+wxh_j)} = Ex_i * Eh_j in the attention inner loop.
__global__ __launch_bounds__(256) void k_proj(
    const float* __restrict__ text,
    const float* __restrict__ Wx_w, const float* __restrict__ Wx_b,
    const float* __restrict__ Wxh_w, const float* __restrict__ Wxh_b,
    float* __restrict__ Ex, float* __restrict__ Eh) {
    int idx = blockIdx.x * 256 + threadIdx.x;   // B*L*N
    int n = idx & 63;
    int bl = idx >> 6;
    const float4* tr = (const float4*)(text + bl * Dd);
    const float4* w1 = (const float4*)(Wx_w + n * Dd);
    const float4* w2 = (const float4*)(Wxh_w + n * Dd);
    float a0 = 0.f, a1 = 0.f;
#pragma unroll
    for (int q = 0; q < 8; ++q) {
        float4 t4 = tr[q]; float4 x4 = w1[q]; float4 y4 = w2[q];
        a0 += t4.x * x4.x + t4.y * x4.y + t4.z * x4.z + t4.w * x4.w;
        a1 += t4.x * y4.x + t4.y * y4.y + t4.z * y4.z + t4.w * y4.w;
    }
    Ex[idx] = fast_exp2(L2E2 * (a0 + Wx_b[n]));
    Eh[idx] = fast_exp2(L2E2 * (a1 + Wxh_b[n]));
}

// ---------------- Kernel 2: fused attention + Xatt + Gx ----------------
// tanh(wxh+wx) = 1 - 2*rcp(E*F+1) with E=e^{2wxh}, F=e^{2wx} precomputed.
// z = sum_n aw_n tanh(.) = awsum - 2*sum_n aw_n*rcp(E_n*F_n+1).
// Epilogue computes Gx = Xatt@W_ih^T + b_ih + b_hh, gate-major rows
// (PyTorch i,f,g,o order) -> Gx[b][t][r0], r0 = gate*64+unit.
__global__ __launch_bounds__(256) void k_attn(
    const float* __restrict__ text,
    const float* __restrict__ Ex, const float* __restrict__ Eh,
    const float* __restrict__ att_w, const float* __restrict__ att_b,
    const float* __restrict__ W_ih, const float* __restrict__ b_ih,
    const float* __restrict__ b_hh, float* __restrict__ Gx) {
    __shared__ float s_eh[64 * 65];    // Eh tile [n][j] padded
    __shared__ float s_text[32 * 65];  // text tile [d][j] padded
    __shared__ float2 s_fa[4 * 64];    // (F, aw) per (wave-row, n)
    __shared__ float s_A[4 * 64];      // per-wave A chunk
    __shared__ __align__(16) float s_xatt[4][32];  // finished Xatt rows

    int tid = threadIdx.x;
    int bx = blockIdx.x;           // 0..1023
    int b = bx >> 7;               // /128
    int i0 = (bx & 127) << 2;      // *4
    int w = tid >> 6, l = tid & 63;
    int i = i0 + w;

    // stage (F, aw) pairs for this block's 4 i-rows
    s_fa[w * 64 + l] = make_float2(Ex[((b * Ll) + i) * Nn + l], att_w[l]);
    float ab = att_b[0];
    __syncthreads();

    float awsum = 0.f;
#pragma unroll
    for (int n = 0; n < 64; ++n) awsum += s_fa[w * 64 + n].y;
    float zc = awsum + ab;

    float xacc = 0.f;              // lane: d = l&31, half = l>>5
    int d = l & 31, hf = l >> 5;

    for (int jt = 0; jt < 8; ++jt) {
        __syncthreads();
        {   // stage Eh tile [n][j] + text tile [d][j]
            int n = tid & 63; int j4 = tid >> 6;
#pragma unroll
            for (int r = 0; r < 16; ++r) {
                int jl = j4 + r * 4;
                s_eh[n * 65 + jl] = Eh[((b * Ll) + jt * 64 + jl) * Nn + n];
            }
            int dd = tid & 31; int j8 = tid >> 5;
#pragma unroll
            for (int r = 0; r < 8; ++r) {
                int jl = j8 + r * 8;
                s_text[dd * 65 + jl] = text[((b * Ll) + jt * 64 + jl) * Dd + dd];
            }
        }
        __syncthreads();
        float S = 0.f;
#pragma unroll
        for (int n = 0; n < 64; ++n) {
            float E = s_eh[n * 65 + l];
            float2 fa = s_fa[w * 64 + n];
            float r = fast_rcp(fmaf(E, fa.x, 1.f));
            S = fmaf(fa.y, r, S);
        }
        // A = sigmoid(awsum - 2S + ab)
        float A = fast_rcp(1.f + fast_exp2(-L2E * (zc - 2.f * S)));
        s_A[w * 64 + l] = A;
#pragma unroll
        for (int jj = 0; jj < 32; ++jj) {
            int j = hf * 32 + jj;
            xacc += s_A[w * 64 + j] * s_text[d * 65 + j];
        }
    }
    xacc += __shfl_xor(xacc, 32);
    if (l < 32) s_xatt[w][l] = xacc;   // lanes 0..31 hold d = l
    __syncthreads();

    // ---- fused Gx epilogue: thread tid = W_ih row r0, rows i0..i0+3 ----
    {
        int r0 = tid;                  // gate-major row 0..255
        const float4* wr = (const float4*)(W_ih + r0 * Dd);
        float4 wv[8];
#pragma unroll
        for (int q = 0; q < 8; ++q) wv[q] = wr[q];
        float bias = b_ih[r0] + b_hh[r0];
#pragma unroll
        for (int r = 0; r < 4; ++r) {
            const float4* xr = (const float4*)s_xatt[r];  // LDS broadcast reads
            float acc = bias;
#pragma unroll
            for (int q = 0; q < 8; ++q) {
                float4 x4 = xr[q]; float4 w4 = wv[q];
                acc += x4.x * w4.x + x4.y * w4.y + x4.z * w4.z + x4.w * w4.w;
            }
            Gx[((b * Ll) + i0 + r) * G4 + r0] = acc;
        }
    }
}

// ---------------- Kernel 3: LSTM recurrence via MFMA (one block per batch) ----------------
// 4 waves. Wave w owns units [16w,16w+16). Per step the matvec
// gates = h @ W_hh^T + Gx[t] runs as 8 MFMAs (4 gate-tiles x 2 K-steps)
// with A row0 = h, rows 1-15 = 0, C_in = Gx (bias absorbed).
// A/B layout: row(col)=lane&15, k=8*(lane>>4)+i. C: col=lane&15,
// row=(lane>>4)*4+reg (m89-verified) -> row0 lives in lanes 0-15, reg 0.
// One barrier/step; h in LDS f16 double-buffer; dist-2 Gx prefetch.
__global__ __launch_bounds__(256) void k_lstm(
    const float* __restrict__ Gx, const float* __restrict__ W_hh,
    const float* __restrict__ dense_w, const float* __restrict__ dense_b,
    float* __restrict__ out) {
    __shared__ __align__(16) _Float16 s_h[2][64];
    int b = blockIdx.x;
    int tid = threadIdx.x;
    int w = tid >> 6, l = tid & 63;
    int lg = l >> 4;               // k-block group (A/B), row group (C)
    int col = l & 15;              // B col offset / C col = unit offset
    bool diag = (col == 0);        // lanes supplying A row 0

    // B fragments: bfrag[gt][ks][i] = W_hh[n][k], n = gt*64+16w+col,
    // k = 8*lg + i + 32*ks  (f32 -> f16 once at start)
    f16x8 bfrag[4][2];
#pragma unroll
    for (int gt = 0; gt < 4; ++gt) {
        const float* wrow = W_hh + (gt * 64 + w * 16 + col) * 64 + lg * 8;
#pragma unroll
        for (int ks = 0; ks < 2; ++ks) {
            const float4* wp = (const float4*)(wrow + ks * 32);
            float4 v0 = wp[0], v1 = wp[1];
            f16x8 f;
            f[0] = (_Float16)v0.x; f[1] = (_Float16)v0.y;
            f[2] = (_Float16)v0.z; f[3] = (_Float16)v0.w;
            f[4] = (_Float16)v1.x; f[5] = (_Float16)v1.y;
            f[6] = (_Float16)v1.z; f[7] = (_Float16)v1.w;
            bfrag[gt][ks] = f;
        }
    }

    if (tid < 64) s_h[0][tid] = (_Float16)0.f;
    float c = 0.f;
    const float* gxb = Gx + (size_t)b * Ll * G4;
    int gxoff = w * 16 + col;      // n = gt*64 + gxoff

    float gx_cur[4], gx_n1[4];
#pragma unroll
    for (int gt = 0; gt < 4; ++gt) {
        gx_cur[gt] = gxb[gt * 64 + gxoff];
        gx_n1[gt]  = gxb[G4 + gt * 64 + gxoff];
    }
    __syncthreads();

    int buf = 0;
    for (int t = 0; t < Ll; ++t) {
        int t2 = (t + 2 < Ll) ? (t + 2) : (Ll - 1);
        float gx_n2[4];
#pragma unroll
        for (int gt = 0; gt < 4; ++gt)
            gx_n2[gt] = gxb[(size_t)t2 * G4 + gt * 64 + gxoff];

        // A fragments: broadcast b128 reads of h (16 f16 = k 0..31 / 32..63)
        union UA { float4 f; f16x8 h; uint4 u; };
        UA ua0, ua1;
        const float4* hb = (const float4*)(&s_h[buf][0]);
        ua0.f = hb[lg];        // ks=0: k = 8*lg .. 8*lg+7
        ua1.f = hb[lg + 4];    // ks=1: k = 32 + 8*lg ..
        if (!diag) {           // rows 1..15 of A are zero
            ua0.u = make_uint4(0, 0, 0, 0);
            ua1.u = make_uint4(0, 0, 0, 0);
        }

        f32x4 acc0 = {gx_cur[0], gx_cur[0], gx_cur[0], gx_cur[0]};
        f32x4 acc1 = {gx_cur[1], gx_cur[1], gx_cur[1], gx_cur[1]};
        f32x4 acc2 = {gx_cur[2], gx_cur[2], gx_cur[2], gx_cur[2]};
        f32x4 acc3 = {gx_cur[3], gx_cur[3], gx_cur[3], gx_cur[3]};

        acc0 = __builtin_amdgcn_mfma_f32_16x16x32_f16(ua0.h, bfrag[0][0], acc0, 0, 0, 0);
        acc1 = __builtin_amdgcn_mfma_f32_16x16x32_f16(ua0.h, bfrag[1][0], acc1, 0, 0, 0);
        acc2 = __builtin_amdgcn_mfma_f32_16x16x32_f16(ua0.h, bfrag[2][0], acc2, 0, 0, 0);
        acc3 = __builtin_amdgcn_mfma_f32_16x16x32_f16(ua0.h, bfrag[3][0], acc3, 0, 0, 0);
        acc0 = __builtin_amdgcn_mfma_f32_16x16x32_f16(ua1.h, bfrag[0][1], acc0, 0, 0, 0);
        acc1 = __builtin_amdgcn_mfma_f32_16x16x32_f16(ua1.h, bfrag[1][1], acc1, 0, 0, 0);
        acc2 = __builtin_amdgcn_mfma_f32_16x16x32_f16(ua1.h, bfrag[2][1], acc2, 0, 0, 0);
        acc3 = __builtin_amdgcn_mfma_f32_16x16x32_f16(ua1.h, bfrag[3][1], acc3, 0, 0, 0);

        // row 0 of C = finished gate pre-activations (lanes 0-15, reg 0)
        float ti = acc0[0], tf = acc1[0], tg = acc2[0], to = acc3[0];
        float gi = sig2(ti);
        float gf = sig2(tf);
        float gg = tanh2(tg);
        float go = sig2(to);
        c = fmaf(gf, c, gi * gg);
        float hh = go * tanh2(c);
        if (l < 16) s_h[buf ^ 1][w * 16 + l] = (_Float16)hh;
        __syncthreads();
        buf ^= 1;
#pragma unroll
        for (int gt = 0; gt < 4; ++gt) {
            gx_cur[gt] = gx_n1[gt];
            gx_n1[gt] = gx_n2[gt];
        }
    }
    // dense head: threads 0,1 compute the two outputs for this batch
    if (tid < 2) {
        float a = dense_b[tid];
        for (int uu = 0; uu < 64; ++uu)
            a += (float)s_h[buf][uu] * dense_w[tid * 64 + uu];
        out[b * 2 + tid] = a;
    }
}

extern "C" void kernel_launch(void* const* d_in, const int* in_sizes, int n_in,
                              void* d_out, int out_size, void* d_ws, size_t ws_size,
                              hipStream_t stream) {
    const float* text    = (const float*)d_in[0];
    const float* Wx_w    = (const float*)d_in[1];
    const float* Wx_b    = (const float*)d_in[2];
    const float* Wxh_w   = (const float*)d_in[3];
    const float* Wxh_b   = (const float*)d_in[4];
    const float* att_w   = (const float*)d_in[5];
    const float* att_b   = (const float*)d_in[6];
    const float* W_ih    = (const float*)d_in[7];
    const float* W_hh    = (const float*)d_in[8];
    const float* b_ih    = (const float*)d_in[9];
    const float* b_hh    = (const float*)d_in[10];
    const float* dense_w = (const float*)d_in[11];
    const float* dense_b = (const float*)d_in[12];

    float* ws   = (float*)d_ws;
    float* Ex   = ws;                 // 8*512*64   = 262144
    float* Eh   = ws + 262144;        // 262144
    float* Gx   = ws + 655360;        // 8*512*256  = 1048576
    float* out  = (float*)d_out;

    hipLaunchKernelGGL(k_proj, dim3((Bb * Ll * Nn) / 256), dim3(256), 0, stream,
                       text, Wx_w, Wx_b, Wxh_w, Wxh_b, Ex, Eh);
    hipLaunchKernelGGL(k_attn, dim3(Bb * (Ll / 4)), dim3(256), 0, stream,
                       text, Ex, Eh, att_w, att_b, W_ih, b_ih, b_hh, Gx);
    hipLaunchKernelGGL(k_lstm, dim3(Bb), dim3(256), 0, stream,
                       Gx, W_hh, dense_w, dense_b, out);
}

// Round 9
// 200.067 us; speedup vs baseline: 1.3962x; 1.2475x over previous
//
#include <hip/hip_runtime.h>
#include <hip/hip_bf16.h>

#define Bb 8
#define Ll 512
#define Dd 32
#define Nn 64
#define Hh 64
#define G4 256  // 4*H

#define L2E  1.4426950408889634f   // log2(e)
#define L2E2 2.8853900817779268f   // 2*log2(e)

typedef _Float16 h2_t __attribute__((ext_vector_type(2)));

__device__ __forceinline__ float fast_rcp(float x) { return __builtin_amdgcn_rcpf(x); }
// v_exp_f32 computes 2^x directly
__device__ __forceinline__ float fast_exp2(float x) { return __builtin_amdgcn_exp2f(x); }

// sigmoid(x) = rcp(1+exp2(-x*log2e)); saturates gracefully, no clamps
__device__ __forceinline__ float sig2(float x) {
    return fast_rcp(1.f + fast_exp2(-L2E * x));
}
// tanh(x) = 2*sigmoid(2x)-1
__device__ __forceinline__ float tanh2(float x) {
    return fmaf(2.f, fast_rcp(1.f + fast_exp2(-L2E2 * x)), -1.f);
}

__device__ __forceinline__ float fdot2(h2_t a, h2_t b, float c) {
#if __has_builtin(__builtin_amdgcn_fdot2)
    return __builtin_amdgcn_fdot2(a, b, c, false);
#else
    return c + (float)a[0] * (float)b[0] + (float)a[1] * (float)b[1];
#endif
}

template<int CTRL>
__device__ __forceinline__ float quad_dpp(float v) {
    return __int_as_float(__builtin_amdgcn_mov_dpp(__float_as_int(v), CTRL, 0xf, 0xf, true));
}
__device__ __forceinline__ float quad_sum(float v) {
    v += quad_dpp<0xB1>(v);   // quad_perm [1,0,3,2]
    v += quad_dpp<0x4E>(v);   // quad_perm [2,3,0,1]
    return v;
}

// ---------------- Kernel 1: exp-space projections ----------------
// Ex = exp2(2*log2e*(text@Wx^T+b)), Eh = exp2(2*log2e*(text@Wxhat^T+b))
// so that e^{2(wx_i+wxh_j)} = Ex_i * Eh_j in the attention inner loop.
__global__ __launch_bounds__(256) void k_proj(
    const float* __restrict__ text,
    const float* __restrict__ Wx_w, const float* __restrict__ Wx_b,
    const float* __restrict__ Wxh_w, const float* __restrict__ Wxh_b,
    float* __restrict__ Ex, float* __restrict__ Eh) {
    int idx = blockIdx.x * 256 + threadIdx.x;   // B*L*N
    int n = idx & 63;
    int bl = idx >> 6;
    const float4* tr = (const float4*)(text + bl * Dd);
    const float4* w1 = (const float4*)(Wx_w + n * Dd);
    const float4* w2 = (const float4*)(Wxh_w + n * Dd);
    float a0 = 0.f, a1 = 0.f;
#pragma unroll
    for (int q = 0; q < 8; ++q) {
        float4 t4 = tr[q]; float4 x4 = w1[q]; float4 y4 = w2[q];
        a0 += t4.x * x4.x + t4.y * x4.y + t4.z * x4.z + t4.w * x4.w;
        a1 += t4.x * y4.x + t4.y * y4.y + t4.z * y4.z + t4.w * y4.w;
    }
    Ex[idx] = fast_exp2(L2E2 * (a0 + Wx_b[n]));
    Eh[idx] = fast_exp2(L2E2 * (a1 + Wxh_b[n]));
}

// ---------------- Kernel 2: fused attention + Xatt + Gx ----------------
// tanh(wxh+wx) = 1 - 2*rcp(E*F+1) with E=e^{2wxh}, F=e^{2wx} precomputed.
// z = sum_n aw_n tanh(.) = awsum - 2*sum_n aw_n*rcp(E_n*F_n+1).
// Layouts chosen for paired LDS reads: s_eh j-major (b64 over n-pairs),
// s_fa read as float4 pairs (b128), s_text/s_A accumulated as float2.
// Epilogue computes Gx = Xatt@W_ih^T + b_ih + b_hh, gate-major rows.
__global__ __launch_bounds__(256) void k_attn(
    const float* __restrict__ text,
    const float* __restrict__ Ex, const float* __restrict__ Eh,
    const float* __restrict__ att_w, const float* __restrict__ att_b,
    const float* __restrict__ W_ih, const float* __restrict__ b_ih,
    const float* __restrict__ b_hh, float* __restrict__ Gx) {
    __shared__ float s_eh[64 * 66];    // [j][n] j-major, pad 66 (8B-aligned rows)
    __shared__ float s_text[32 * 66];  // [d][j] padded 66
    __shared__ float2 s_fa[4 * 64];    // (F, aw) per (wave-row, n)
    __shared__ float s_A[4 * 64];      // per-wave A chunk
    __shared__ __align__(16) float s_xatt[4][32];  // finished Xatt rows

    int tid = threadIdx.x;
    int bx = blockIdx.x;           // 0..1023
    int b = bx >> 7;               // /128
    int i0 = (bx & 127) << 2;      // *4
    int w = tid >> 6, l = tid & 63;
    int i = i0 + w;

    // stage (F, aw) pairs for this block's 4 i-rows
    s_fa[w * 64 + l] = make_float2(Ex[((b * Ll) + i) * Nn + l], att_w[l]);
    float ab = att_b[0];
    __syncthreads();

    float awsum = 0.f;
#pragma unroll
    for (int n = 0; n < 64; ++n) awsum += s_fa[w * 64 + n].y;
    float zc = awsum + ab;

    float xacc = 0.f;              // lane: d = l&31, half = l>>5
    int d = l & 31, hf = l >> 5;

    for (int jt = 0; jt < 8; ++jt) {
        __syncthreads();
        {   // stage Eh tile j-major [j][n] + text tile [d][j]
            int n = tid & 63; int j4 = tid >> 6;
#pragma unroll
            for (int r = 0; r < 16; ++r) {
                int jl = j4 + r * 4;
                s_eh[jl * 66 + n] = Eh[((b * Ll) + jt * 64 + jl) * Nn + n];
            }
            int dd = tid & 31; int j8 = tid >> 5;
#pragma unroll
            for (int r = 0; r < 8; ++r) {
                int jl = j8 + r * 8;
                s_text[dd * 66 + jl] = text[((b * Ll) + jt * 64 + jl) * Dd + dd];
            }
        }
        __syncthreads();
        float S = 0.f;
        const float* ehrow = &s_eh[l * 66];
        const float2* farow = &s_fa[w * 64];
#pragma unroll
        for (int n = 0; n < 64; n += 2) {
            float2 E2 = *(const float2*)(ehrow + n);          // ds_read_b64
            float4 fa2 = *(const float4*)(farow + n);         // ds_read_b128 (F0,aw0,F1,aw1)
            float r0 = fast_rcp(fmaf(E2.x, fa2.x, 1.f));
            S = fmaf(fa2.y, r0, S);
            float r1 = fast_rcp(fmaf(E2.y, fa2.z, 1.f));
            S = fmaf(fa2.w, r1, S);
        }
        // A = sigmoid(awsum - 2S + ab)
        float A = fast_rcp(1.f + fast_exp2(-L2E * (zc - 2.f * S)));
        s_A[w * 64 + l] = A;
#pragma unroll
        for (int jj = 0; jj < 32; jj += 2) {
            int j = hf * 32 + jj;
            float2 A2 = *(const float2*)&s_A[w * 64 + j];
            float2 T2 = *(const float2*)&s_text[d * 66 + j];
            xacc = fmaf(A2.x, T2.x, fmaf(A2.y, T2.y, xacc));
        }
    }
    xacc += __shfl_xor(xacc, 32);
    if (l < 32) s_xatt[w][l] = xacc;   // lanes 0..31 hold d = l
    __syncthreads();

    // ---- fused Gx epilogue: thread tid = W_ih row r0 (gate-major), rows i0..i0+3 ----
    {
        int r0 = tid;                  // gate-major row 0..255
        const float4* wr = (const float4*)(W_ih + r0 * Dd);
        float4 wv[8];
#pragma unroll
        for (int q = 0; q < 8; ++q) wv[q] = wr[q];
        float bias = b_ih[r0] + b_hh[r0];
#pragma unroll
        for (int r = 0; r < 4; ++r) {
            const float4* xr = (const float4*)s_xatt[r];  // LDS broadcast reads
            float acc = bias;
#pragma unroll
            for (int q = 0; q < 8; ++q) {
                float4 x4 = xr[q]; float4 w4 = wv[q];
                acc += x4.x * w4.x + x4.y * w4.y + x4.z * w4.z + x4.w * w4.w;
            }
            Gx[((b * Ll) + i0 + r) * G4 + r0] = acc;
        }
    }
}

// ---------------- Kernel 3: LSTM recurrence (one block per batch) ----------------
// PROVEN 152-us structure (R5): 4 waves. Lane: part p = l&3 (16-elem h slice),
// unit u = w*16 + (l>>2). h in LDS as f16; W_hh as half2 in VGPRs; partial
// dots via v_dot2_f32_f16; quad DPP allreduce; lean exp2/rcp activations
// (all-4 redundant per lane). c fp32/lane. 1 barrier/step, dist-2 Gx prefetch.
__global__ __launch_bounds__(256) void k_lstm(
    const float* __restrict__ Gx, const float* __restrict__ W_hh,
    const float* __restrict__ dense_w, const float* __restrict__ dense_b,
    float* __restrict__ out) {
    __shared__ __align__(16) _Float16 s_h[2][64];
    int b = blockIdx.x;
    int tid = threadIdx.x;
    int w = tid >> 6, l = tid & 63;
    int p = l & 3;                 // h-slice [16p, 16p+16)
    int u = w * 16 + (l >> 2);     // unit

    // wreg[g][q] = half2 of W_hh[g*64+u][p*16 + 2q .. +2)
    h2_t wreg[4][8];
#pragma unroll
    for (int g = 0; g < 4; ++g) {
        const float4* wp = (const float4*)(W_hh + (g * 64 + u) * 64 + p * 16);
#pragma unroll
        for (int q = 0; q < 4; ++q) {
            float4 v = wp[q];
            wreg[g][2 * q]     = h2_t{(_Float16)v.x, (_Float16)v.y};
            wreg[g][2 * q + 1] = h2_t{(_Float16)v.z, (_Float16)v.w};
        }
    }

    if (tid < 64) s_h[0][tid] = (_Float16)0.f;
    float c = 0.f;
    const float* gxb = Gx + (size_t)b * Ll * G4;
    int gidx = p * 64 + u;         // this lane's gx element (gate p, unit u)
    float gx_cur = gxb[gidx];             // t = 0
    float gx_n1  = gxb[G4 + gidx];        // t = 1
    __syncthreads();

    int buf = 0;
    for (int t = 0; t < Ll; ++t) {
        int t2 = (t + 2 < Ll) ? (t + 2) : (Ll - 1);
        float gx_n2 = gxb[(size_t)t2 * G4 + gidx];   // dist-2 prefetch

        // read this lane's 16-half slice of h as 2 x b128
        union { float4 f; h2_t h[4]; } u0, u1;
        u0.f = *(const float4*)(&s_h[buf][p * 16]);
        u1.f = *(const float4*)(&s_h[buf][p * 16 + 8]);

        float a0 = (p == 0) ? gx_cur : 0.f;
        float a1 = (p == 1) ? gx_cur : 0.f;
        float a2 = (p == 2) ? gx_cur : 0.f;
        float a3 = (p == 3) ? gx_cur : 0.f;
#pragma unroll
        for (int q = 0; q < 4; ++q) {
            a0 = fdot2(u0.h[q], wreg[0][q], a0);
            a1 = fdot2(u0.h[q], wreg[1][q], a1);
            a2 = fdot2(u0.h[q], wreg[2][q], a2);
            a3 = fdot2(u0.h[q], wreg[3][q], a3);
        }
#pragma unroll
        for (int q = 0; q < 4; ++q) {
            a0 = fdot2(u1.h[q], wreg[0][q + 4], a0);
            a1 = fdot2(u1.h[q], wreg[1][q + 4], a1);
            a2 = fdot2(u1.h[q], wreg[2][q + 4], a2);
            a3 = fdot2(u1.h[q], wreg[3][q + 4], a3);
        }
        // quad reduce: every lane gets all four gate totals (bit-identical)
        float ti = quad_sum(a0);
        float tf = quad_sum(a1);
        float tg = quad_sum(a2);
        float to = quad_sum(a3);

        float gi = sig2(ti);
        float gf = sig2(tf);
        float gg = tanh2(tg);
        float go = sig2(to);
        c = fmaf(gf, c, gi * gg);
        float hh = go * tanh2(c);
        if (p == 0) s_h[buf ^ 1][u] = (_Float16)hh;
        __syncthreads();
        buf ^= 1;
        gx_cur = gx_n1;
        gx_n1 = gx_n2;
    }
    if (tid == 0) {   // dense head for this batch row
        float a0 = dense_b[0], a1 = dense_b[1];
        for (int uu = 0; uu < 64; ++uu) {
            float hv = (float)s_h[buf][uu];
            a0 += hv * dense_w[uu];
            a1 += hv * dense_w[64 + uu];
        }
        out[b * 2 + 0] = a0;
        out[b * 2 + 1] = a1;
    }
}

extern "C" void kernel_launch(void* const* d_in, const int* in_sizes, int n_in,
                              void* d_out, int out_size, void* d_ws, size_t ws_size,
                              hipStream_t stream) {
    const float* text    = (const float*)d_in[0];
    const float* Wx_w    = (const float*)d_in[1];
    const float* Wx_b    = (const float*)d_in[2];
    const float* Wxh_w   = (const float*)d_in[3];
    const float* Wxh_b   = (const float*)d_in[4];
    const float* att_w   = (const float*)d_in[5];
    const float* att_b   = (const float*)d_in[6];
    const float* W_ih    = (const float*)d_in[7];
    const float* W_hh    = (const float*)d_in[8];
    const float* b_ih    = (const float*)d_in[9];
    const float* b_hh    = (const float*)d_in[10];
    const float* dense_w = (const float*)d_in[11];
    const float* dense_b = (const float*)d_in[12];

    float* ws   = (float*)d_ws;
    float* Ex   = ws;                 // 8*512*64   = 262144
    float* Eh   = ws + 262144;        // 262144
    float* Gx   = ws + 655360;        // 8*512*256  = 1048576
    float* out  = (float*)d_out;

    hipLaunchKernelGGL(k_proj, dim3((Bb * Ll * Nn) / 256), dim3(256), 0, stream,
                       text, Wx_w, Wx_b, Wxh_w, Wxh_b, Ex, Eh);
    hipLaunchKernelGGL(k_attn, dim3(Bb * (Ll / 4)), dim3(256), 0, stream,
                       text, Ex, Eh, att_w, att_b, W_ih, b_ih, b_hh, Gx);
    hipLaunchKernelGGL(k_lstm, dim3(Bb), dim3(256), 0, stream,
                       Gx, W_hh, dense_w, dense_b, out);
}